// Round 6
// baseline (172.813 us; speedup 1.0000x reference)
//
#include <hip/hip_runtime.h>

typedef unsigned short u16;
typedef unsigned int u32;
typedef __bf16 bf16x8 __attribute__((ext_vector_type(8)));
typedef float f32x4 __attribute__((ext_vector_type(4)));
typedef u16 u16x8 __attribute__((ext_vector_type(8)));
typedef u32 u32x2 __attribute__((ext_vector_type(2)));

#define NB 64
#define NN 512
#define NH 12
#define HD 32
#define DIM 384

static constexpr size_t QWS = (size_t)NB * NH * NN * HD;  // bf16 elems per tensor
#define LOG2E 1.4426950408889634f
#define QSCALE 0.25503486f   // (1/sqrt(32)) * log2(e)

__device__ __forceinline__ u16 f2bf(float f) {
  __bf16 b = (__bf16)f;
  union { __bf16 b; u16 u; } v; v.b = b;
  return v.u;
}
__device__ __forceinline__ float lo16f(u32 w) {
  union { u32 u; float f; } v; v.u = w << 16;
  return v.f;
}
__device__ __forceinline__ float hi16f(u32 w) {
  union { u32 u; float f; } v; v.u = w & 0xffff0000u;
  return v.f;
}

// ---------------------------------------------------------------------------
// Kernel 1: expand relative-position bias to [H][N][N] bf16, pre-scaled log2e
// ---------------------------------------------------------------------------
__global__ __launch_bounds__(256) void bias_expand_k(const float* __restrict__ table,
                                                     const int* __restrict__ rel,
                                                     u16* __restrict__ be) {
  int t = blockIdx.x * 256 + threadIdx.x;
  int idx = rel[t];
  const float* row = table + (size_t)idx * NH;
#pragma unroll
  for (int h = 0; h < NH; ++h)
    be[(size_t)h * (NN * NN) + t] = f2bf(row[h] * LOG2E);
}

// ---------------------------------------------------------------------------
// Kernel 2: fused QKV projection GEMM (q gets (x+qb)*QSCALE folded in).
// ---------------------------------------------------------------------------
__global__ __launch_bounds__(256) void qkv_proj_k(const float* __restrict__ x1,
                                                  const float* __restrict__ x2,
                                                  const float* __restrict__ Wq,
                                                  const float* __restrict__ Wkv,
                                                  const float* __restrict__ qb,
                                                  const float* __restrict__ vb,
                                                  u16* __restrict__ q_ws,
                                                  u16* __restrict__ k_ws,
                                                  u16* __restrict__ v_ws) {
  const int g = blockIdx.x;                    // 0..2303
  const int v = (g & 7) * 288 + (g >> 3);      // chunk per XCD
  const int ct = v % 9;
  const int m0 = (v / 9) * 128;
  const int j0 = ct * 128;
  const float* A;
  const float* W;
  int type;
  if (ct < 3)      { A = x1; W = Wq  + (size_t)j0 * DIM;         type = 0; }
  else if (ct < 6) { A = x2; W = Wkv + (size_t)(j0 - 384) * DIM; type = 1; }
  else             { A = x2; W = Wkv + (size_t)(j0 - 384) * DIM; type = 2; }

  __shared__ u16 As[128][72];
  __shared__ u16 Bs[128][72];

  const int tid = threadIdx.x;
  const int lane = tid & 63, wid = tid >> 6;
  const int wm = (wid >> 1) * 64, wn = (wid & 1) * 64;
  const int lg = lane >> 4, lr = lane & 15;
  const int srow = tid >> 3;
  const int scol = (tid & 7) * 8;

  f32x4 acc[4][4] = {};

  for (int k0 = 0; k0 < DIM; k0 += 64) {
    __syncthreads();
#pragma unroll
    for (int rr = 0; rr < 4; ++rr) {
      int r = srow + rr * 32;
      const float* src = A + (size_t)(m0 + r) * DIM + k0 + scol;
      float4 f0 = *(const float4*)src;
      float4 f1 = *(const float4*)(src + 4);
      u16x8 tmp = {f2bf(f0.x), f2bf(f0.y), f2bf(f0.z), f2bf(f0.w),
                   f2bf(f1.x), f2bf(f1.y), f2bf(f1.z), f2bf(f1.w)};
      *(u16x8*)&As[r][scol] = tmp;
      const float* srcB = W + (size_t)r * DIM + k0 + scol;
      float4 g0 = *(const float4*)srcB;
      float4 g1 = *(const float4*)(srcB + 4);
      u16x8 tmpB = {f2bf(g0.x), f2bf(g0.y), f2bf(g0.z), f2bf(g0.w),
                    f2bf(g1.x), f2bf(g1.y), f2bf(g1.z), f2bf(g1.w)};
      *(u16x8*)&Bs[r][scol] = tmpB;
    }
    __syncthreads();
#pragma unroll
    for (int kk = 0; kk < 2; ++kk) {
      bf16x8 af[4], bfv[4];
#pragma unroll
      for (int mf = 0; mf < 4; ++mf)
        af[mf] = *(const bf16x8*)&As[wm + mf * 16 + lr][kk * 32 + lg * 8];
#pragma unroll
      for (int nf = 0; nf < 4; ++nf)
        bfv[nf] = *(const bf16x8*)&Bs[wn + nf * 16 + lr][kk * 32 + lg * 8];
#pragma unroll
      for (int mf = 0; mf < 4; ++mf)
#pragma unroll
        for (int nf = 0; nf < 4; ++nf)
          acc[mf][nf] = __builtin_amdgcn_mfma_f32_16x16x32_bf16(af[mf], bfv[nf], acc[mf][nf], 0, 0, 0);
    }
  }

  const int b = m0 >> 9;
  u16* dst = (type == 0) ? q_ws : (type == 1 ? k_ws : v_ws);
  const float scale = (type == 0) ? QSCALE : 1.0f;
#pragma unroll
  for (int nf = 0; nf < 4; ++nf) {
    int j = j0 + wn + nf * 16 + lr;
    int jj = j - ((type == 0) ? 0 : (type == 1 ? 384 : 768));
    float bv = (type == 0) ? qb[jj] : (type == 2 ? vb[jj] : 0.0f);
    int h = jj >> 5, d = jj & 31;
    u16* dcol = dst + (((size_t)b * NH + h) * NN) * HD + d;
#pragma unroll
    for (int mf = 0; mf < 4; ++mf) {
      int nbase = (m0 & 511) + wm + mf * 16 + lg * 4;
#pragma unroll
      for (int r = 0; r < 4; ++r) {
        float val = (acc[mf][nf][r] + bv) * scale;
        dcol[(size_t)(nbase + r) * HD] = f2bf(val);
      }
    }
  }
}

// ---------------------------------------------------------------------------
// Kernel 3: attention, swapped QK + k-permuted V (zero-shuffle PV).
//   - bias as MFMA C operand, register-prefetched one k-tile ahead
//   - K fragments from global (coalesced 1KB/wave, L1/L2), prefetched ahead
//   - only V^T (permuted) in LDS: 33 KB -> 3 blocks/CU resident, no tail
//   - exp via __builtin_amdgcn_exp2f; row-sum on VALU (8 adds/iter)
// ---------------------------------------------------------------------------
__global__ __launch_bounds__(512, 4) void attn_k(const u16* __restrict__ qw,
                                                 const u16* __restrict__ kw,
                                                 const u16* __restrict__ vw,
                                                 const u16* __restrict__ be,
                                                 float* __restrict__ out) {
  const int g = blockIdx.x;                 // 0..767
  const int vv = (g & 7) * 96 + (g >> 3);   // chunk per XCD
  const int h = vv >> 6, b = vv & 63;
  const size_t base = ((size_t)b * NH + h) * NN * HD;
  const u16* Q = qw + base;
  const u16* K = kw + base;
  const u16* V = vw + base;
  const u16* bias = be + (size_t)h * NN * NN;

  __shared__ u16 Vtp[HD][520];   // [d][k-permuted], 1040B stride

  const int tid = threadIdx.x;
  const int lane = tid & 63, w = tid >> 6;
  const int lg = lane >> 4, lr = lane & 15;
  const int q0 = w * 64;

  // Q fragments (B-operand of QK^T)
  bf16x8 qf[4];
#pragma unroll
  for (int mf = 0; mf < 4; ++mf)
    qf[mf] = *(const bf16x8*)&Q[(q0 + mf * 16 + lr) * HD + lg * 8];

  // stage V transposed with permuted key columns
  for (int c = tid; c < 2048; c += 512) {
    int row = c >> 2, part = (c & 3) * 8;
    u16x8 vld = *(const u16x8*)&V[row * HD + part];
    int kk = row & 31;
    int col = (row & ~31) + ((kk >> 2) & 3) * 8 + (kk >> 4) * 4 + (kk & 3);
#pragma unroll
    for (int j = 0; j < 8; ++j) Vtp[part + j][col] = vld[j];
  }

  // per-lane bases
  const u16* kfp = K + lr * HD + lg * 8;
  const u32* brow = (const u32*)bias + (size_t)(q0 + lr) * (NN / 2) + lg * 2;

  // prefetch kt=0 (K fragments + bias words) while V staging settles
  bf16x8 kc0 = *(const bf16x8*)(kfp);
  bf16x8 kc1 = *(const bf16x8*)(kfp + 16 * HD);
  u32x2 bw0[4], bw1[4];
#pragma unroll
  for (int mf = 0; mf < 4; ++mf) {
    bw0[mf] = *(const u32x2*)(brow + mf * 4096);
    bw1[mf] = *(const u32x2*)(brow + mf * 4096 + 8);
  }

  __syncthreads();

  f32x4 accOT[4][2] = {};
  float lsum[4] = {0.f, 0.f, 0.f, 0.f};

  for (int kt = 0; kt < 16; ++kt) {
    const int k0 = kt * 32;
    // prefetch next k-tile (clamped at the last tile; loads are L1/L2 hits)
    const int kn = (kt < 15) ? k0 + 32 : k0;
    bf16x8 kn0 = *(const bf16x8*)(kfp + (size_t)kn * HD);
    bf16x8 kn1 = *(const bf16x8*)(kfp + (size_t)(kn + 16) * HD);
    u32x2 bn0[4], bn1[4];
#pragma unroll
    for (int mf = 0; mf < 4; ++mf) {
      bn0[mf] = *(const u32x2*)(brow + mf * 4096 + (kn >> 1));
      bn1[mf] = *(const u32x2*)(brow + mf * 4096 + (kn >> 1) + 8);
    }
    bf16x8 vp0 = *(const bf16x8*)&Vtp[lr][k0 + lg * 8];
    bf16x8 vp1 = *(const bf16x8*)&Vtp[16 + lr][k0 + lg * 8];
#pragma unroll
    for (int mf = 0; mf < 4; ++mf) {
      f32x4 c0 = {lo16f(bw0[mf].x), hi16f(bw0[mf].x), lo16f(bw0[mf].y), hi16f(bw0[mf].y)};
      f32x4 c1 = {lo16f(bw1[mf].x), hi16f(bw1[mf].x), lo16f(bw1[mf].y), hi16f(bw1[mf].y)};
      f32x4 s0 = __builtin_amdgcn_mfma_f32_16x16x32_bf16(kc0, qf[mf], c0, 0, 0, 0);
      f32x4 s1 = __builtin_amdgcn_mfma_f32_16x16x32_bf16(kc1, qf[mf], c1, 0, 0, 0);
      float p0[4], p1[4];
#pragma unroll
      for (int r = 0; r < 4; ++r) {
        p0[r] = __builtin_amdgcn_exp2f(s0[r]);
        p1[r] = __builtin_amdgcn_exp2f(s1[r]);
      }
      lsum[mf] += ((p0[0] + p0[1]) + (p0[2] + p0[3])) +
                  ((p1[0] + p1[1]) + (p1[2] + p1[3]));
      bf16x8 pv = {(__bf16)p0[0], (__bf16)p0[1], (__bf16)p0[2], (__bf16)p0[3],
                   (__bf16)p1[0], (__bf16)p1[1], (__bf16)p1[2], (__bf16)p1[3]};
      accOT[mf][0] = __builtin_amdgcn_mfma_f32_16x16x32_bf16(vp0, pv, accOT[mf][0], 0, 0, 0);
      accOT[mf][1] = __builtin_amdgcn_mfma_f32_16x16x32_bf16(vp1, pv, accOT[mf][1], 0, 0, 0);
    }
    // rotate prefetch buffers
    kc0 = kn0; kc1 = kn1;
#pragma unroll
    for (int mf = 0; mf < 4; ++mf) { bw0[mf] = bn0[mf]; bw1[mf] = bn1[mf]; }
  }

  // reduce row-sums across lg groups (bits 4,5 of lane)
  float linv[4];
#pragma unroll
  for (int mf = 0; mf < 4; ++mf) {
    float s = lsum[mf];
    s += __shfl_xor(s, 16, 64);
    s += __shfl_xor(s, 32, 64);
    linv[mf] = 1.0f / s;
  }

  // O^T[d = nf*16 + lg*4 + r][q = q0 + mf*16 + lr] -> out[b][q][h*32+d], float4
  float* outp = out + ((size_t)b * NN) * DIM + h * HD;
#pragma unroll
  for (int mf = 0; mf < 4; ++mf) {
    int q = q0 + mf * 16 + lr;
#pragma unroll
    for (int nf = 0; nf < 2; ++nf) {
      float4 o = {accOT[mf][nf][0] * linv[mf], accOT[mf][nf][1] * linv[mf],
                  accOT[mf][nf][2] * linv[mf], accOT[mf][nf][3] * linv[mf]};
      *(float4*)&outp[(size_t)q * DIM + nf * 16 + lg * 4] = o;
    }
  }
}

// ---------------------------------------------------------------------------
extern "C" void kernel_launch(void* const* d_in, const int* in_sizes, int n_in,
                              void* d_out, int out_size, void* d_ws, size_t ws_size,
                              hipStream_t stream) {
  const float* x1    = (const float*)d_in[0];
  const float* x2    = (const float*)d_in[1];
  const float* Wq    = (const float*)d_in[2];
  const float* Wkv   = (const float*)d_in[3];
  const float* qb    = (const float*)d_in[4];
  const float* vb    = (const float*)d_in[5];
  const float* table = (const float*)d_in[6];
  const int*   rel   = (const int*)d_in[7];
  float* out = (float*)d_out;

  u16* ws   = (u16*)d_ws;
  u16* q_ws = ws;
  u16* k_ws = ws + QWS;
  u16* v_ws = ws + 2 * QWS;
  u16* be   = ws + 3 * QWS;

  bias_expand_k<<<(NN * NN) / 256, 256, 0, stream>>>(table, rel, be);
  qkv_proj_k<<<2304, 256, 0, stream>>>(x1, x2, Wq, Wkv, qb, vb, q_ws, k_ws, v_ws);
  attn_k<<<NB * NH, 512, 0, stream>>>(q_ws, k_ws, v_ws, be, out);
}

// Round 7
// 120.287 us; speedup vs baseline: 1.4367x; 1.4367x over previous
//
#include <hip/hip_runtime.h>

typedef unsigned short u16;
typedef unsigned int u32;
typedef __bf16 bf16x8 __attribute__((ext_vector_type(8)));
typedef float f32x4 __attribute__((ext_vector_type(4)));
typedef u16 u16x8 __attribute__((ext_vector_type(8)));
typedef u32 u32x4 __attribute__((ext_vector_type(4)));

#define NB 64
#define NN 512
#define NH 12
#define HD 32
#define DIM 384

static constexpr size_t QWS = (size_t)NB * NH * NN * HD;  // bf16 elems per tensor
#define LOG2E 1.4426950408889634f
#define QSCALE 0.25503486f   // (1/sqrt(32)) * log2(e)

__device__ __forceinline__ u16 f2bf(float f) {
  __bf16 b = (__bf16)f;
  union { __bf16 b; u16 u; } v; v.b = b;
  return v.u;
}
__device__ __forceinline__ float lo16f(u32 w) {
  union { u32 u; float f; } v; v.u = w << 16;
  return v.f;
}
__device__ __forceinline__ float hi16f(u32 w) {
  union { u32 u; float f; } v; v.u = w & 0xffff0000u;
  return v.f;
}

// ---------------------------------------------------------------------------
// Kernel 1: expand relative-position bias DIRECTLY into MFMA-fragment order:
//   beR[h][kt][wave][mf][lane][word]  (u32 = 2 packed bf16, pre-scaled log2e)
//   so the attention wave reads one contiguous 1KB dwordx4 stream per (kt,mf).
//   Mapping: lane=(lg,lr); q = wave*64 + mf*16 + lr;
//            k = kt*32 + (word>>1)*16 + lg*4 + (word&1)*2 + {0,1}.
// ---------------------------------------------------------------------------
__global__ __launch_bounds__(256) void bias_expand_k(const float* __restrict__ table,
                                                     const int* __restrict__ rel,
                                                     u32* __restrict__ beR) {
  int t = blockIdx.x * 256 + threadIdx.x;   // 1,572,864 words total
  int word = t & 3;
  int lane = (t >> 2) & 63;
  int mf   = (t >> 8) & 3;
  int wv   = (t >> 10) & 7;
  int kt   = (t >> 13) & 15;
  int h    = t >> 17;                       // 0..11
  int lr = lane & 15, lg = lane >> 4;
  int q = wv * 64 + mf * 16 + lr;
  int k = kt * 32 + (word >> 1) * 16 + lg * 4 + (word & 1) * 2;
  int i0 = rel[q * NN + k];
  int i1 = rel[q * NN + k + 1];
  u16 b0 = f2bf(table[i0 * NH + h] * LOG2E);
  u16 b1 = f2bf(table[i1 * NH + h] * LOG2E);
  beR[t] = (u32)b0 | ((u32)b1 << 16);
}

// ---------------------------------------------------------------------------
// Kernel 2: fused QKV projection GEMM (q gets (x+qb)*QSCALE folded in).
// ---------------------------------------------------------------------------
__global__ __launch_bounds__(256) void qkv_proj_k(const float* __restrict__ x1,
                                                  const float* __restrict__ x2,
                                                  const float* __restrict__ Wq,
                                                  const float* __restrict__ Wkv,
                                                  const float* __restrict__ qb,
                                                  const float* __restrict__ vb,
                                                  u16* __restrict__ q_ws,
                                                  u16* __restrict__ k_ws,
                                                  u16* __restrict__ v_ws) {
  const int g = blockIdx.x;                    // 0..2303
  const int v = (g & 7) * 288 + (g >> 3);      // chunk per XCD
  const int ct = v % 9;
  const int m0 = (v / 9) * 128;
  const int j0 = ct * 128;
  const float* A;
  const float* W;
  int type;
  if (ct < 3)      { A = x1; W = Wq  + (size_t)j0 * DIM;         type = 0; }
  else if (ct < 6) { A = x2; W = Wkv + (size_t)(j0 - 384) * DIM; type = 1; }
  else             { A = x2; W = Wkv + (size_t)(j0 - 384) * DIM; type = 2; }

  __shared__ u16 As[128][72];
  __shared__ u16 Bs[128][72];

  const int tid = threadIdx.x;
  const int lane = tid & 63, wid = tid >> 6;
  const int wm = (wid >> 1) * 64, wn = (wid & 1) * 64;
  const int lg = lane >> 4, lr = lane & 15;
  const int srow = tid >> 3;
  const int scol = (tid & 7) * 8;

  f32x4 acc[4][4] = {};

  for (int k0 = 0; k0 < DIM; k0 += 64) {
    __syncthreads();
#pragma unroll
    for (int rr = 0; rr < 4; ++rr) {
      int r = srow + rr * 32;
      const float* src = A + (size_t)(m0 + r) * DIM + k0 + scol;
      float4 f0 = *(const float4*)src;
      float4 f1 = *(const float4*)(src + 4);
      u16x8 tmp = {f2bf(f0.x), f2bf(f0.y), f2bf(f0.z), f2bf(f0.w),
                   f2bf(f1.x), f2bf(f1.y), f2bf(f1.z), f2bf(f1.w)};
      *(u16x8*)&As[r][scol] = tmp;
      const float* srcB = W + (size_t)r * DIM + k0 + scol;
      float4 g0 = *(const float4*)srcB;
      float4 g1 = *(const float4*)(srcB + 4);
      u16x8 tmpB = {f2bf(g0.x), f2bf(g0.y), f2bf(g0.z), f2bf(g0.w),
                    f2bf(g1.x), f2bf(g1.y), f2bf(g1.z), f2bf(g1.w)};
      *(u16x8*)&Bs[r][scol] = tmpB;
    }
    __syncthreads();
#pragma unroll
    for (int kk = 0; kk < 2; ++kk) {
      bf16x8 af[4], bfv[4];
#pragma unroll
      for (int mf = 0; mf < 4; ++mf)
        af[mf] = *(const bf16x8*)&As[wm + mf * 16 + lr][kk * 32 + lg * 8];
#pragma unroll
      for (int nf = 0; nf < 4; ++nf)
        bfv[nf] = *(const bf16x8*)&Bs[wn + nf * 16 + lr][kk * 32 + lg * 8];
#pragma unroll
      for (int mf = 0; mf < 4; ++mf)
#pragma unroll
        for (int nf = 0; nf < 4; ++nf)
          acc[mf][nf] = __builtin_amdgcn_mfma_f32_16x16x32_bf16(af[mf], bfv[nf], acc[mf][nf], 0, 0, 0);
    }
  }

  const int b = m0 >> 9;
  u16* dst = (type == 0) ? q_ws : (type == 1 ? k_ws : v_ws);
  const float scale = (type == 0) ? QSCALE : 1.0f;
#pragma unroll
  for (int nf = 0; nf < 4; ++nf) {
    int j = j0 + wn + nf * 16 + lr;
    int jj = j - ((type == 0) ? 0 : (type == 1 ? 384 : 768));
    float bv = (type == 0) ? qb[jj] : (type == 2 ? vb[jj] : 0.0f);
    int h = jj >> 5, d = jj & 31;
    u16* dcol = dst + (((size_t)b * NH + h) * NN) * HD + d;
#pragma unroll
    for (int mf = 0; mf < 4; ++mf) {
      int nbase = (m0 & 511) + wm + mf * 16 + lg * 4;
#pragma unroll
      for (int r = 0; r < 4; ++r) {
        float val = (acc[mf][nf][r] + bv) * scale;
        dcol[(size_t)(nbase + r) * HD] = f2bf(val);
      }
    }
  }
}

// ---------------------------------------------------------------------------
// Kernel 3: attention, swapped QK + k-permuted V (zero-shuffle PV).
//   - bias from the fragment-ordered beR: one coalesced dwordx4 per (kt,mf)
//     (64 lanes read 1KB contiguous; sequential stream across kt)
//   - K and V^T(permuted) in LDS (74KB, 2 blocks/CU)
//   - exp via __builtin_amdgcn_exp2f
// ---------------------------------------------------------------------------
__global__ __launch_bounds__(512, 4) void attn_k(const u16* __restrict__ qw,
                                                 const u16* __restrict__ kw,
                                                 const u16* __restrict__ vw,
                                                 const u32* __restrict__ beR,
                                                 float* __restrict__ out) {
  const int g = blockIdx.x;                 // 0..767
  const int vv = (g & 7) * 96 + (g >> 3);   // chunk per XCD
  const int h = vv >> 6, b = vv & 63;
  const size_t base = ((size_t)b * NH + h) * NN * HD;
  const u16* Q = qw + base;
  const u16* K = kw + base;
  const u16* V = vw + base;

  __shared__ u16 Ks[NN][40];     // [k][d], 80B stride
  __shared__ u16 Vtp[HD][520];   // [d][k-permuted], 1040B stride

  const int tid = threadIdx.x;
  const int lane = tid & 63, w = tid >> 6;
  const int lg = lane >> 4, lr = lane & 15;
  const int q0 = w * 64;

  // Q fragments (B-operand of QK^T)
  bf16x8 qf[4];
#pragma unroll
  for (int mf = 0; mf < 4; ++mf)
    qf[mf] = *(const bf16x8*)&Q[(q0 + mf * 16 + lr) * HD + lg * 8];

  // stage K row-major; V transposed with permuted key columns
  for (int c = tid; c < 2048; c += 512) {
    int row = c >> 2, part = (c & 3) * 8;
    *(u16x8*)&Ks[row][part] = *(const u16x8*)&K[row * HD + part];
    u16x8 vld = *(const u16x8*)&V[row * HD + part];
    int kk = row & 31;
    int col = (row & ~31) + ((kk >> 2) & 3) * 8 + (kk >> 4) * 4 + (kk & 3);
#pragma unroll
    for (int j = 0; j < 8; ++j) Vtp[part + j][col] = vld[j];
  }
  __syncthreads();

  // bias stream base for this (h, wave): beR[h][kt][w][mf][lane][0..3]
  const u32* bstream = beR + ((((size_t)h * 16) * 8 + w) * 4) * 256 + lane * 4;

  f32x4 accOT[4][2] = {};
  float lsum[4] = {0.f, 0.f, 0.f, 0.f};

  for (int kt = 0; kt < 16; ++kt) {
    const int k0 = kt * 32;
    const u32* bkt = bstream + (size_t)kt * 8192;   // 8*4*256 words per kt step
    bf16x8 kf0 = *(const bf16x8*)&Ks[k0 + lr][lg * 8];
    bf16x8 kf1 = *(const bf16x8*)&Ks[k0 + 16 + lr][lg * 8];
    bf16x8 vp0 = *(const bf16x8*)&Vtp[lr][k0 + lg * 8];
    bf16x8 vp1 = *(const bf16x8*)&Vtp[16 + lr][k0 + lg * 8];
#pragma unroll
    for (int mf = 0; mf < 4; ++mf) {
      u32x4 bb = *(const u32x4*)(bkt + mf * 256);
      f32x4 c0 = {lo16f(bb.x), hi16f(bb.x), lo16f(bb.y), hi16f(bb.y)};
      f32x4 c1 = {lo16f(bb.z), hi16f(bb.z), lo16f(bb.w), hi16f(bb.w)};
      f32x4 s0 = __builtin_amdgcn_mfma_f32_16x16x32_bf16(kf0, qf[mf], c0, 0, 0, 0);
      f32x4 s1 = __builtin_amdgcn_mfma_f32_16x16x32_bf16(kf1, qf[mf], c1, 0, 0, 0);
      float p0[4], p1[4];
#pragma unroll
      for (int r = 0; r < 4; ++r) {
        p0[r] = __builtin_amdgcn_exp2f(s0[r]);
        p1[r] = __builtin_amdgcn_exp2f(s1[r]);
      }
      lsum[mf] += ((p0[0] + p0[1]) + (p0[2] + p0[3])) +
                  ((p1[0] + p1[1]) + (p1[2] + p1[3]));
      bf16x8 pv = {(__bf16)p0[0], (__bf16)p0[1], (__bf16)p0[2], (__bf16)p0[3],
                   (__bf16)p1[0], (__bf16)p1[1], (__bf16)p1[2], (__bf16)p1[3]};
      accOT[mf][0] = __builtin_amdgcn_mfma_f32_16x16x32_bf16(vp0, pv, accOT[mf][0], 0, 0, 0);
      accOT[mf][1] = __builtin_amdgcn_mfma_f32_16x16x32_bf16(vp1, pv, accOT[mf][1], 0, 0, 0);
    }
  }

  // reduce row-sums across lg groups (bits 4,5 of lane)
  float linv[4];
#pragma unroll
  for (int mf = 0; mf < 4; ++mf) {
    float s = lsum[mf];
    s += __shfl_xor(s, 16, 64);
    s += __shfl_xor(s, 32, 64);
    linv[mf] = 1.0f / s;
  }

  // O^T[d = nf*16 + lg*4 + r][q = q0 + mf*16 + lr] -> out[b][q][h*32+d], float4
  float* outp = out + ((size_t)b * NN) * DIM + h * HD;
#pragma unroll
  for (int mf = 0; mf < 4; ++mf) {
    int q = q0 + mf * 16 + lr;
#pragma unroll
    for (int nf = 0; nf < 2; ++nf) {
      float4 o = {accOT[mf][nf][0] * linv[mf], accOT[mf][nf][1] * linv[mf],
                  accOT[mf][nf][2] * linv[mf], accOT[mf][nf][3] * linv[mf]};
      *(float4*)&outp[(size_t)q * DIM + nf * 16 + lg * 4] = o;
    }
  }
}

// ---------------------------------------------------------------------------
extern "C" void kernel_launch(void* const* d_in, const int* in_sizes, int n_in,
                              void* d_out, int out_size, void* d_ws, size_t ws_size,
                              hipStream_t stream) {
  const float* x1    = (const float*)d_in[0];
  const float* x2    = (const float*)d_in[1];
  const float* Wq    = (const float*)d_in[2];
  const float* Wkv   = (const float*)d_in[3];
  const float* qb    = (const float*)d_in[4];
  const float* vb    = (const float*)d_in[5];
  const float* table = (const float*)d_in[6];
  const int*   rel   = (const int*)d_in[7];
  float* out = (float*)d_out;

  u16* ws   = (u16*)d_ws;
  u16* q_ws = ws;
  u16* k_ws = ws + QWS;
  u16* v_ws = ws + 2 * QWS;
  u32* beR  = (u32*)(ws + 3 * QWS);   // 1,572,864 u32 = 6.3 MB

  bias_expand_k<<<6144, 256, 0, stream>>>(table, rel, beR);
  qkv_proj_k<<<2304, 256, 0, stream>>>(x1, x2, Wq, Wkv, qb, vb, q_ws, k_ws, v_ws);
  attn_k<<<NB * NH, 512, 0, stream>>>(q_ws, k_ws, v_ws, beR, out);
}

// Round 8
// 107.122 us; speedup vs baseline: 1.6132x; 1.1229x over previous
//
#include <hip/hip_runtime.h>

typedef unsigned short u16;
typedef unsigned int u32;
typedef __bf16 bf16x8 __attribute__((ext_vector_type(8)));
typedef float f32x4 __attribute__((ext_vector_type(4)));
typedef u16 u16x8 __attribute__((ext_vector_type(8)));
typedef u32 u32x4 __attribute__((ext_vector_type(4)));

#define NB 64
#define NN 512
#define NH 12
#define HD 32
#define DIM 384

static constexpr size_t QWS = (size_t)NB * NH * NN * HD;  // bf16 elems per tensor
#define LOG2E 1.4426950408889634f
#define QSCALE 0.25503486f   // (1/sqrt(32)) * log2(e)

__device__ __forceinline__ u16 f2bf(float f) {
  __bf16 b = (__bf16)f;
  union { __bf16 b; u16 u; } v; v.b = b;
  return v.u;
}
__device__ __forceinline__ float lo16f(u32 w) {
  union { u32 u; float f; } v; v.u = w << 16;
  return v.f;
}
__device__ __forceinline__ float hi16f(u32 w) {
  union { u32 u; float f; } v; v.u = w & 0xffff0000u;
  return v.f;
}
__device__ __forceinline__ void gload16(const void* g, void* l) {
  __builtin_amdgcn_global_load_lds((const __attribute__((address_space(1))) u32*)g,
                                   (__attribute__((address_space(3))) u32*)l, 16, 0, 0);
}

// ---------------------------------------------------------------------------
// Kernel 1 (prep): blocks [0,6144): bias -> fragment-stream beR (as R7).
//                  blocks [6144,6360): W f32 -> fragment-stream Wf bf16:
//                  Wf[colblk 72][kk 12][lane 64][8], j = cb*16+lr, k = kk*32+lg*8+e.
// ---------------------------------------------------------------------------
__global__ __launch_bounds__(256) void prep_k(const float* __restrict__ table,
                                              const int* __restrict__ rel,
                                              const float* __restrict__ Wq,
                                              const float* __restrict__ Wkv,
                                              u32* __restrict__ beR,
                                              u16* __restrict__ Wf) {
  int bid = blockIdx.x;
  if (bid < 6144) {
    int t = bid * 256 + threadIdx.x;   // 1,572,864 words
    int word = t & 3;
    int lane = (t >> 2) & 63;
    int mf   = (t >> 8) & 3;
    int wv   = (t >> 10) & 7;
    int kt   = (t >> 13) & 15;
    int h    = t >> 17;
    int lr = lane & 15, lg = lane >> 4;
    int q = wv * 64 + mf * 16 + lr;
    int k = kt * 32 + (word >> 1) * 16 + lg * 4 + (word & 1) * 2;
    int i0 = rel[q * NN + k];
    int i1 = rel[q * NN + k + 1];
    u16 b0 = f2bf(table[i0 * NH + h] * LOG2E);
    u16 b1 = f2bf(table[i1 * NH + h] * LOG2E);
    beR[t] = (u32)b0 | ((u32)b1 << 16);
  } else {
    int t2 = (bid - 6144) * 256 + threadIdx.x;   // 0..55295
    int lane = t2 & 63;
    int kk = (t2 >> 6) % 12;
    int cb = t2 / (12 * 64);
    int j = cb * 16 + (lane & 15);
    int k = kk * 32 + (lane >> 4) * 8;
    const float* wrow = (j < 384) ? (Wq + (size_t)j * DIM) : (Wkv + (size_t)(j - 384) * DIM);
    float4 a = *(const float4*)(wrow + k);
    float4 b = *(const float4*)(wrow + k + 4);
    u16x8 o = {f2bf(a.x), f2bf(a.y), f2bf(a.z), f2bf(a.w),
               f2bf(b.x), f2bf(b.y), f2bf(b.z), f2bf(b.w)};
    *(u16x8*)(Wf + (size_t)t2 * 8) = o;
  }
}

// ---------------------------------------------------------------------------
// Kernel 2: QKV projection, fragment-stream W + register A.
//   512 blocks x 512 thr: bid<256 -> kv (x2, colblks 24..71), else q (x1, 0..23).
//   Wave w owns rows m0+w*16..+15: A-frags = in-lane f32->bf16 cvt (x read ONCE).
//   W staged per 24KB chunk (2 colblks) via global_load_lds, double-buffered;
//   LDS reads at lane*16 -> conflict-free. Epilogue scatters to [b][h][n][d].
// ---------------------------------------------------------------------------
__global__ __launch_bounds__(512, 4) void qkv_proj_k(const float* __restrict__ x1,
                                                     const float* __restrict__ x2,
                                                     const float* __restrict__ qb,
                                                     const float* __restrict__ vb,
                                                     const u16* __restrict__ Wf,
                                                     u16* __restrict__ q_ws,
                                                     u16* __restrict__ k_ws,
                                                     u16* __restrict__ v_ws) {
  __shared__ __attribute__((aligned(16))) u16 Wbuf[2][12288];  // 2 x 24KB

  const int bid = blockIdx.x;
  const int is_q = bid >= 256;
  const int m0 = (bid & 255) * 128;
  const int tid = threadIdx.x, lane = tid & 63, w = tid >> 6;
  const int lg = lane >> 4, lr = lane & 15;
  const float* X = is_q ? x1 : x2;
  const int cb0 = is_q ? 0 : 24;
  const int nch = is_q ? 12 : 24;
  const char* wsrc = (const char*)(Wf + (size_t)cb0 * 12 * 64 * 8);
  const int bb = m0 >> 9;

  // A fragments: rows m0 + w*16 + lr, all K, in registers (48 VGPR)
  bf16x8 af[12];
  const float* xrow = X + (size_t)(m0 + w * 16 + lr) * DIM + lg * 8;
#pragma unroll
  for (int kk = 0; kk < 12; ++kk) {
    float4 a = *(const float4*)(xrow + kk * 32);
    float4 b = *(const float4*)(xrow + kk * 32 + 4);
    af[kk] = (bf16x8){(__bf16)a.x, (__bf16)a.y, (__bf16)a.z, (__bf16)a.w,
                      (__bf16)b.x, (__bf16)b.y, (__bf16)b.z, (__bf16)b.w};
  }

  // stage chunk 0
#pragma unroll
  for (int i = 0; i < 3; ++i) {
    int inst = w + i * 8;
    gload16(wsrc + inst * 1024 + lane * 16, (char*)&Wbuf[0][0] + inst * 1024 + lane * 16);
  }
  __syncthreads();

  for (int c = 0; c < nch; ++c) {
    if (c + 1 < nch) {
      const char* s = wsrc + (size_t)(c + 1) * 24576;
      char* d = (char*)&Wbuf[(c + 1) & 1][0];
#pragma unroll
      for (int i = 0; i < 3; ++i) {
        int inst = w + i * 8;
        gload16(s + inst * 1024 + lane * 16, d + inst * 1024 + lane * 16);
      }
    }
    const u16* wb = &Wbuf[c & 1][0];
#pragma unroll
    for (int lc = 0; lc < 2; ++lc) {
      f32x4 acc = {0.f, 0.f, 0.f, 0.f};
#pragma unroll
      for (int kk = 0; kk < 12; ++kk) {
        bf16x8 wf = *(const bf16x8*)(wb + ((lc * 12 + kk) * 64 + lane) * 8);
        acc = __builtin_amdgcn_mfma_f32_16x16x32_bf16(af[kk], wf, acc, 0, 0, 0);
      }
      // epilogue for colblk cb = cb0 + c*2 + lc
      int j = (cb0 + c * 2 + lc) * 16 + lr;
      int jj = is_q ? j : (j < 768 ? j - 384 : j - 768);
      float bv = is_q ? qb[jj] : (j >= 768 ? vb[jj] : 0.0f);
      float scale = is_q ? QSCALE : 1.0f;
      u16* dst = is_q ? q_ws : (j < 768 ? k_ws : v_ws);
      int hh = jj >> 5, dd = jj & 31;
      size_t basead = ((size_t)(bb * NH + hh) * NN) * HD + dd;
      int rowb = (m0 & 511) + w * 16 + lg * 4;
#pragma unroll
      for (int r = 0; r < 4; ++r)
        dst[basead + (size_t)(rowb + r) * HD] = f2bf((acc[r] + bv) * scale);
    }
    __syncthreads();
  }
}

// ---------------------------------------------------------------------------
// Kernel 3: attention (unchanged from R7): swapped QK + k-permuted V,
// fragment-stream bias as MFMA C operand.
// ---------------------------------------------------------------------------
__global__ __launch_bounds__(512, 4) void attn_k(const u16* __restrict__ qw,
                                                 const u16* __restrict__ kw,
                                                 const u16* __restrict__ vw,
                                                 const u32* __restrict__ beR,
                                                 float* __restrict__ out) {
  const int g = blockIdx.x;                 // 0..767
  const int vv = (g & 7) * 96 + (g >> 3);   // chunk per XCD
  const int h = vv >> 6, b = vv & 63;
  const size_t base = ((size_t)b * NH + h) * NN * HD;
  const u16* Q = qw + base;
  const u16* K = kw + base;
  const u16* V = vw + base;

  __shared__ u16 Ks[NN][40];     // [k][d], 80B stride
  __shared__ u16 Vtp[HD][520];   // [d][k-permuted], 1040B stride

  const int tid = threadIdx.x;
  const int lane = tid & 63, w = tid >> 6;
  const int lg = lane >> 4, lr = lane & 15;
  const int q0 = w * 64;

  bf16x8 qf[4];
#pragma unroll
  for (int mf = 0; mf < 4; ++mf)
    qf[mf] = *(const bf16x8*)&Q[(q0 + mf * 16 + lr) * HD + lg * 8];

  for (int c = tid; c < 2048; c += 512) {
    int row = c >> 2, part = (c & 3) * 8;
    *(u16x8*)&Ks[row][part] = *(const u16x8*)&K[row * HD + part];
    u16x8 vld = *(const u16x8*)&V[row * HD + part];
    int kk = row & 31;
    int col = (row & ~31) + ((kk >> 2) & 3) * 8 + (kk >> 4) * 4 + (kk & 3);
#pragma unroll
    for (int j = 0; j < 8; ++j) Vtp[part + j][col] = vld[j];
  }
  __syncthreads();

  const u32* bstream = beR + ((((size_t)h * 16) * 8 + w) * 4) * 256 + lane * 4;

  f32x4 accOT[4][2] = {};
  float lsum[4] = {0.f, 0.f, 0.f, 0.f};

  for (int kt = 0; kt < 16; ++kt) {
    const int k0 = kt * 32;
    const u32* bkt = bstream + (size_t)kt * 8192;
    bf16x8 kf0 = *(const bf16x8*)&Ks[k0 + lr][lg * 8];
    bf16x8 kf1 = *(const bf16x8*)&Ks[k0 + 16 + lr][lg * 8];
    bf16x8 vp0 = *(const bf16x8*)&Vtp[lr][k0 + lg * 8];
    bf16x8 vp1 = *(const bf16x8*)&Vtp[16 + lr][k0 + lg * 8];
#pragma unroll
    for (int mf = 0; mf < 4; ++mf) {
      u32x4 bbv = *(const u32x4*)(bkt + mf * 256);
      f32x4 c0 = {lo16f(bbv.x), hi16f(bbv.x), lo16f(bbv.y), hi16f(bbv.y)};
      f32x4 c1 = {lo16f(bbv.z), hi16f(bbv.z), lo16f(bbv.w), hi16f(bbv.w)};
      f32x4 s0 = __builtin_amdgcn_mfma_f32_16x16x32_bf16(kf0, qf[mf], c0, 0, 0, 0);
      f32x4 s1 = __builtin_amdgcn_mfma_f32_16x16x32_bf16(kf1, qf[mf], c1, 0, 0, 0);
      float p0[4], p1[4];
#pragma unroll
      for (int r = 0; r < 4; ++r) {
        p0[r] = __builtin_amdgcn_exp2f(s0[r]);
        p1[r] = __builtin_amdgcn_exp2f(s1[r]);
      }
      lsum[mf] += ((p0[0] + p0[1]) + (p0[2] + p0[3])) +
                  ((p1[0] + p1[1]) + (p1[2] + p1[3]));
      bf16x8 pv = {(__bf16)p0[0], (__bf16)p0[1], (__bf16)p0[2], (__bf16)p0[3],
                   (__bf16)p1[0], (__bf16)p1[1], (__bf16)p1[2], (__bf16)p1[3]};
      accOT[mf][0] = __builtin_amdgcn_mfma_f32_16x16x32_bf16(vp0, pv, accOT[mf][0], 0, 0, 0);
      accOT[mf][1] = __builtin_amdgcn_mfma_f32_16x16x32_bf16(vp1, pv, accOT[mf][1], 0, 0, 0);
    }
  }

  float linv[4];
#pragma unroll
  for (int mf = 0; mf < 4; ++mf) {
    float s = lsum[mf];
    s += __shfl_xor(s, 16, 64);
    s += __shfl_xor(s, 32, 64);
    linv[mf] = 1.0f / s;
  }

  float* outp = out + ((size_t)b * NN) * DIM + h * HD;
#pragma unroll
  for (int mf = 0; mf < 4; ++mf) {
    int q = q0 + mf * 16 + lr;
#pragma unroll
    for (int nf = 0; nf < 2; ++nf) {
      float4 o = {accOT[mf][nf][0] * linv[mf], accOT[mf][nf][1] * linv[mf],
                  accOT[mf][nf][2] * linv[mf], accOT[mf][nf][3] * linv[mf]};
      *(float4*)&outp[(size_t)q * DIM + nf * 16 + lg * 4] = o;
    }
  }
}

// ---------------------------------------------------------------------------
extern "C" void kernel_launch(void* const* d_in, const int* in_sizes, int n_in,
                              void* d_out, int out_size, void* d_ws, size_t ws_size,
                              hipStream_t stream) {
  const float* x1    = (const float*)d_in[0];
  const float* x2    = (const float*)d_in[1];
  const float* Wq    = (const float*)d_in[2];
  const float* Wkv   = (const float*)d_in[3];
  const float* qb    = (const float*)d_in[4];
  const float* vb    = (const float*)d_in[5];
  const float* table = (const float*)d_in[6];
  const int*   rel   = (const int*)d_in[7];
  float* out = (float*)d_out;

  u16* ws   = (u16*)d_ws;
  u16* q_ws = ws;
  u16* k_ws = ws + QWS;
  u16* v_ws = ws + 2 * QWS;
  u32* beR  = (u32*)(ws + 3 * QWS);          // 1,572,864 u32 = 6.3 MB
  u16* Wf   = ws + 3 * QWS + 2 * 1572864;    // 442,368 u16 = 0.88 MB

  prep_k<<<6360, 256, 0, stream>>>(table, rel, Wq, Wkv, beR, Wf);
  qkv_proj_k<<<512, 512, 0, stream>>>(x1, x2, qb, vb, Wf, q_ws, k_ws, v_ws);
  attn_k<<<NB * NH, 512, 0, stream>>>(q_ws, k_ws, v_ws, beR, out);
}